// Round 5
// baseline (404.717 us; speedup 1.0000x reference)
//
#include <hip/hip_runtime.h>
#include <hip/hip_bf16.h>
#include <hip/hip_cooperative_groups.h>
#include <math.h>

namespace cg = cooperative_groups;

// Problem constants (fixed by the reference)
constexpr int Bn = 32768;   // batch
constexpr int Dn = 256;     // embedding dim
constexpr int Cn = 2048;    // classes
constexpr int NSPLIT = 8;                 // class splits in main phase
constexpr int CLS_PER_BLK = Cn / NSPLIT;  // 256
constexpr int NIT = CLS_PER_BLK / 16;     // 16 class-tiles per unit
constexpr int NU = (Bn / 256) * NSPLIT;   // 1024 work units
#define EPSF 1e-12f
#define INFF __builtin_inff()

typedef __bf16 bf16x8 __attribute__((ext_vector_type(8)));
typedef __bf16 bf16x4 __attribute__((ext_vector_type(4)));
typedef float  f32x4  __attribute__((ext_vector_type(4)));

__device__ inline void async_copy16(const void* g, void* l) {
    __builtin_amdgcn_global_load_lds(
        (const __attribute__((address_space(1))) void*)g,
        (__attribute__((address_space(3))) void*)l, 16, 0, 0);
}

// Single fused cooperative kernel. Phases separated by grid-wide sync.
// Occupancy: ~244 unified VGPR+AGPR in P5 -> 2 blocks/CU; grid sized by
// the occupancy API at launch (all phases are grid-stride safe).
__global__ __launch_bounds__(256, 2) void k_fused(
    const float* __restrict__ feat, const int* __restrict__ labels,
    const int* __restrict__ epoch,
    __bf16* fneg, int* hist, int* cnt_i, int* offs, int* offs_wk, int* order,
    __bf16* centK, float* cn2x, float* minval, float* dotown,
    float* accum, float* out)
{
    __shared__ __align__(16) __bf16 sB[2][16 * Dn];   // 16 KB double buffer
    __shared__ float s_cn2[CLS_PER_BLK];               // 1 KB
    __shared__ int s_part[256];                        // 1 KB (scan)

    cg::grid_group gg = cg::this_grid();
    const int tid = threadIdx.x;
    const int gtid = blockIdx.x * 256 + tid;
    const int nthreads = gridDim.x * 256;
    const int nwaves = nthreads >> 6;
    const int wave_id = gtid >> 6;
    const int lane = tid & 63;
    const int wave = tid >> 6;

    // ---- P0: zero hist + accum (d_ws is poisoned before every call) ----
    for (int c = gtid; c < Cn; c += nthreads) hist[c] = 0;
    if (gtid < 2) accum[gtid] = 0.0f;
    gg.sync();

    // ---- P1: normalize, prescale by -2, store bf16; histogram ----
    for (int s = wave_id; s < Bn; s += nwaves) {
        const float4 v = ((const float4*)(feat + (size_t)s * Dn))[lane];
        float ss = v.x * v.x + v.y * v.y + v.z * v.z + v.w * v.w;
        #pragma unroll
        for (int off = 1; off < 64; off <<= 1) ss += __shfl_xor(ss, off, 64);
        const float inv = -2.0f / fmaxf(sqrtf(ss), EPSF);
        bf16x4 bf;
        bf[0] = (__bf16)(v.x * inv); bf[1] = (__bf16)(v.y * inv);
        bf[2] = (__bf16)(v.z * inv); bf[3] = (__bf16)(v.w * inv);
        *(bf16x4*)(fneg + (size_t)s * Dn + lane * 4) = bf;
        if (lane == 0) atomicAdd(&hist[labels[s]], 1);
    }
    gg.sync();

    // ---- P2: exclusive scan of 2048-bin histogram (block 0 only) ----
    if (blockIdx.x == 0) {
        int h[8], pre[8]; int sum = 0;
        #pragma unroll
        for (int j = 0; j < 8; ++j) { h[j] = hist[tid * 8 + j]; pre[j] = sum; sum += h[j]; }
        int v = sum;
        s_part[tid] = v; __syncthreads();
        for (int off = 1; off < 256; off <<= 1) {
            int add = (tid >= off) ? s_part[tid - off] : 0;
            __syncthreads();
            v += add; s_part[tid] = v;
            __syncthreads();
        }
        const int base = v - sum;
        #pragma unroll
        for (int j = 0; j < 8; ++j) {
            const int b = tid * 8 + j, o = base + pre[j];
            cnt_i[b] = h[j]; offs[b] = o; offs_wk[b] = o;
        }
    }
    gg.sync();

    // ---- P3: scatter sample indices by class (counting sort) ----
    for (int i = gtid; i < Bn; i += nthreads) {
        const int pos = atomicAdd(&offs_wk[labels[i]], 1);
        order[pos] = i;
    }
    gg.sync();

    // ---- P4: per-class sums -> centK (K-major bf16) + cn2 ----
    for (int c = wave_id; c < Cn; c += nwaves) {
        const int n = cnt_i[c], start = offs[c];
        int myidx = 0;
        if (lane < n) myidx = order[start + lane];
        float sx = 0.f, sy = 0.f, sz = 0.f, sw = 0.f;
        const int nf = (n < 64) ? n : 64;
        for (int j = 0; j < nf; ++j) {
            const int idx = __shfl(myidx, j, 64);
            const bf16x4 v = *(const bf16x4*)(fneg + (size_t)idx * Dn + lane * 4);
            sx += -0.5f * (float)v[0]; sy += -0.5f * (float)v[1];
            sz += -0.5f * (float)v[2]; sw += -0.5f * (float)v[3];
        }
        for (int j = 64; j < n; ++j) {      // overflow fallback (rare)
            const int idx = order[start + j];
            const bf16x4 v = *(const bf16x4*)(fneg + (size_t)idx * Dn + lane * 4);
            sx += -0.5f * (float)v[0]; sy += -0.5f * (float)v[1];
            sz += -0.5f * (float)v[2]; sw += -0.5f * (float)v[3];
        }
        const float invn = 1.0f / fmaxf((float)n, 1.0f);
        const float cx = sx * invn, cy = sy * invn, cz = sz * invn, cw = sw * invn;
        // centK chunk (kc, c): dims [8kc,8kc+8); lane covers kc=lane>>1, half lane&1
        bf16x4 cb; cb[0] = (__bf16)cx; cb[1] = (__bf16)cy;
        cb[2] = (__bf16)cz; cb[3] = (__bf16)cw;
        *(bf16x4*)(centK + ((size_t)(lane >> 1) * Cn + c) * 8 + (lane & 1) * 4) = cb;
        float ss = cx * cx + cy * cy + cz * cz + cw * cw;
        #pragma unroll
        for (int off = 1; off < 64; off <<= 1) ss += __shfl_xor(ss, off, 64);
        if (lane == 0) cn2x[c] = (n > 0) ? ss : INFF;
    }
    gg.sync();

    // ---- P5: MFMA dot + masked min + own-class dot extraction ----
    // unit u -> (bx = u & 127, by = u >> 7): grid-stride keeps bx constant
    // per block when gridDim divides 512. A = -2f, so cn2+acc = d^2-1.
    const int m16 = lane & 15, quad = lane >> 4;
    for (int u = blockIdx.x; u < NU; u += gridDim.x) {
        const int bx = u & 127, by = u >> 7;
        const int sbase = bx * 256 + wave * 64;
        const int c_begin = by * CLS_PER_BLK;

        bf16x8 a[4][8];
        #pragma unroll
        for (int p = 0; p < 4; ++p) {
            const __bf16* fr = fneg + (size_t)(sbase + p * 16 + m16) * Dn + quad * 8;
            #pragma unroll
            for (int t = 0; t < 8; ++t) a[p][t] = *(const bf16x8*)(fr + t * 32);
        }
        int lab[4][4];
        #pragma unroll
        for (int p = 0; p < 4; ++p)
            #pragma unroll
            for (int r = 0; r < 4; ++r)
                lab[p][r] = labels[sbase + p * 16 + quad * 4 + r];

        float rm[4][4], dacc[4][4];
        #pragma unroll
        for (int p = 0; p < 4; ++p)
            #pragma unroll
            for (int r = 0; r < 4; ++r) { rm[p][r] = INFF; dacc[p][r] = 0.0f; }

        auto stage = [&](int buf, int it) {
            const int c0 = c_begin + it * 16;
            #pragma unroll
            for (int j = 0; j < 2; ++j) {
                const int chunk = wave * 128 + j * 64 + lane;     // 0..511
                const int kc = chunk >> 4, n = chunk & 15;
                const __bf16* g = centK + ((size_t)kc * Cn + (c0 + n)) * 8;
                __bf16* l = &sB[buf][(size_t)(wave * 128 + j * 64) * 8];
                async_copy16(g, l);
            }
        };

        stage(0, 0);
        for (int c = tid; c < CLS_PER_BLK; c += 256) s_cn2[c] = cn2x[c_begin + c];
        __syncthreads();
        for (int it = 0; it < NIT; ++it) {
            const int cur = it & 1;
            if (it + 1 < NIT) stage(cur ^ 1, it + 1);
            const float cn2v = s_cn2[it * 16 + m16];
            const __bf16* ls = &sB[cur][0];
            f32x4 acc[4] = {{0.f,0.f,0.f,0.f},{0.f,0.f,0.f,0.f},
                            {0.f,0.f,0.f,0.f},{0.f,0.f,0.f,0.f}};
            #pragma unroll
            for (int t = 0; t < 8; ++t) {
                const bf16x8 b = *(const bf16x8*)(ls + t * 512 + lane * 8);
                #pragma unroll
                for (int p = 0; p < 4; ++p)
                    acc[p] = __builtin_amdgcn_mfma_f32_16x16x32_bf16(a[p][t], b, acc[p], 0, 0, 0);
            }
            const int crow = c_begin + it * 16 + m16;
            #pragma unroll
            for (int p = 0; p < 4; ++p)
                #pragma unroll
                for (int r = 0; r < 4; ++r) {
                    const bool own = (crow == lab[p][r]);
                    const float sel = own ? INFF : cn2v;
                    rm[p][r] = fminf(rm[p][r], sel + acc[p][r]);
                    dacc[p][r] += own ? acc[p][r] : 0.0f;
                }
            __syncthreads();
        }
        #pragma unroll
        for (int off = 1; off < 16; off <<= 1)
            #pragma unroll
            for (int p = 0; p < 4; ++p)
                #pragma unroll
                for (int r = 0; r < 4; ++r) {
                    rm[p][r] = fminf(rm[p][r], __shfl_xor(rm[p][r], off, 64));
                    dacc[p][r] += __shfl_xor(dacc[p][r], off, 64);
                }
        if (m16 == 0) {
            float* mv = minval + (size_t)by * Bn;
            float* dv = dotown + (size_t)by * Bn;
            #pragma unroll
            for (int p = 0; p < 4; ++p)
                #pragma unroll
                for (int r = 0; r < 4; ++r) {
                    mv[sbase + p * 16 + quad * 4 + r] = rm[p][r];
                    dv[sbase + p * 16 + quad * 4 + r] = dacc[p][r];
                }
        }
    }
    gg.sync();

    // ---- P6: d_p (algebraic), d_n, softplus, reduce ----
    {
        const float temp = fminf(0.3f + 0.02f * (float)(*epoch), 1.0f);
        float ws = 0.0f, wc = 0.0f;
        for (int i = gtid; i < Bn; i += nthreads) {
            float m = minval[i];
            float draw = dotown[i];             // = -2 * f.c_own (one split nonzero)
            #pragma unroll
            for (int k = 1; k < NSPLIT; ++k) {
                m = fminf(m, minval[(size_t)k * Bn + i]);
                draw += dotown[(size_t)k * Bn + i];
            }
            const int l = labels[i];
            const int n = cnt_i[l];
            const float nf = (float)n;
            const float cn2 = cn2x[l];          // finite (n >= 1)
            const float fds = nf * (-0.5f * draw);      // f.s
            const float fm1 = fmaxf(nf - 1.0f, 1.0f);
            const float fdcp = (fds - 1.0f) / fm1;
            const float cp2 = (nf * nf * cn2 - 2.0f * fds + 1.0f) / (fm1 * fm1);
            const float dp2 = 1.0f - 2.0f * fdcp + cp2;
            const float d_p = sqrtf(fmaxf(dp2, 0.0f) + EPSF);
            const bool finite = (m < 1e37f);
            const float d_n = finite ? sqrtf(fmaxf(1.0f + m, EPSF)) : 0.0f;
            const bool valid = (n > 1) && finite;
            const float x = (d_p - d_n) / temp;
            const float sp = fmaxf(x, 0.0f) + log1pf(expf(-fabsf(x)));
            ws += valid ? sp : 0.0f;
            wc += valid ? 1.0f : 0.0f;
        }
        #pragma unroll
        for (int off = 1; off < 64; off <<= 1) {
            ws += __shfl_xor(ws, off, 64);
            wc += __shfl_xor(wc, off, 64);
        }
        if (lane == 0) {
            atomicAdd(&accum[0], ws);
            atomicAdd(&accum[1], wc);
        }
    }
    gg.sync();

    // ---- P7: finalize ----
    if (gtid == 0) {
        const float s = accum[0], c = accum[1];
        out[0] = (c > 0.0f) ? (s / fmaxf(c, 1.0f)) : 0.0f;   // WEIGHT = 1.0
    }
}

// ---------------- launch ---------------------------------------------------
extern "C" void kernel_launch(void* const* d_in, const int* in_sizes, int n_in,
                              void* d_out, int out_size, void* d_ws, size_t ws_size,
                              hipStream_t stream) {
    const float* feat  = (const float*)d_in[0];
    const int* labels  = (const int*)d_in[1];
    const int* epoch   = (const int*)d_in[2];
    float* out = (float*)d_out;
    char* ws = (char*)d_ws;

    size_t off = 0;
    __bf16* fneg   = (__bf16*)(ws + off); off += (size_t)Bn * Dn * 2;      // 16 MiB
    __bf16* centK  = (__bf16*)(ws + off); off += (size_t)Cn * Dn * 2;      //  1 MiB
    float*  cn2x   = (float*)(ws + off);  off += (size_t)Cn * 4;
    int*    hist   = (int*)(ws + off);    off += (size_t)Cn * 4;
    int*    cnt_i  = (int*)(ws + off);    off += (size_t)Cn * 4;
    int*    offsp  = (int*)(ws + off);    off += (size_t)Cn * 4;
    int*    offs_wk= (int*)(ws + off);    off += (size_t)Cn * 4;
    int*    order  = (int*)(ws + off);    off += (size_t)Bn * 4;
    float*  minval = (float*)(ws + off);  off += (size_t)NSPLIT * Bn * 4;  //  1 MiB
    float*  dotown = (float*)(ws + off);  off += (size_t)NSPLIT * Bn * 4;  //  1 MiB
    float*  accum  = (float*)(ws + off);  off += 2 * 4;

    int maxb = 0;
    if (hipOccupancyMaxActiveBlocksPerMultiprocessor(
            &maxb, (const void*)k_fused, 256, 0) != hipSuccess || maxb < 1)
        maxb = 1;
    int grid = maxb * 256;          // 256 CUs on MI355X
    if (grid > 1024) grid = 1024;   // no more than NU units anyway

    void* args[] = {(void*)&feat, (void*)&labels, (void*)&epoch,
                    (void*)&fneg, (void*)&hist, (void*)&cnt_i, (void*)&offsp,
                    (void*)&offs_wk, (void*)&order, (void*)&centK, (void*)&cn2x,
                    (void*)&minval, (void*)&dotown, (void*)&accum, (void*)&out};
    (void)hipLaunchCooperativeKernel((const void*)k_fused, dim3(grid), dim3(256),
                                     args, 0, stream);
}

// Round 6
// 344.668 us; speedup vs baseline: 1.1742x; 1.1742x over previous
//
#include <hip/hip_runtime.h>
#include <hip/hip_bf16.h>
#include <math.h>

// Problem constants (fixed by the reference)
constexpr int Bn = 32768;   // batch
constexpr int Dn = 256;     // embedding dim
constexpr int Cn = 2048;    // classes
constexpr int NSPLIT = 4;                // class splits in k_main
constexpr int CLS_PER_BLK = Cn / NSPLIT; // 512
constexpr int NSUP = CLS_PER_BLK / 32;   // 16 supertiles (32 classes) per unit
#define EPSF 1e-12f
#define INFF __builtin_inff()

typedef __bf16 bf16x8 __attribute__((ext_vector_type(8)));
typedef __bf16 bf16x4 __attribute__((ext_vector_type(4)));
typedef float  f32x4  __attribute__((ext_vector_type(4)));

__device__ inline void async_copy16(const void* g, void* l) {
    __builtin_amdgcn_global_load_lds(
        (const __attribute__((address_space(1))) void*)g,
        (__attribute__((address_space(3))) void*)l, 16, 0, 0);
}

// ---------------- K1: normalize(-2x, bf16) + histogram; last block scans --
// wave per sample; lane covers 4 dims. fneg[i] = -2 * f_i (bf16).
__global__ __launch_bounds__(256) void k_prep(const float* __restrict__ feat,
                                              const int* __restrict__ labels,
                                              __bf16* __restrict__ fneg,
                                              int* __restrict__ hist,
                                              int* __restrict__ cnt_i,
                                              int* __restrict__ offs,
                                              int* __restrict__ offs_wk,
                                              int* __restrict__ ticket) {
    const int tid = threadIdx.x;
    const int wave = tid >> 6, lane = tid & 63;
    const int s = blockIdx.x * 4 + wave;
    const float4 v = ((const float4*)(feat + (size_t)s * Dn))[lane];
    float ss = v.x * v.x + v.y * v.y + v.z * v.z + v.w * v.w;
    #pragma unroll
    for (int off = 1; off < 64; off <<= 1) ss += __shfl_xor(ss, off, 64);
    const float inv = -2.0f / fmaxf(sqrtf(ss), EPSF);
    bf16x4 bf;
    bf[0] = (__bf16)(v.x * inv); bf[1] = (__bf16)(v.y * inv);
    bf[2] = (__bf16)(v.z * inv); bf[3] = (__bf16)(v.w * inv);
    *(bf16x4*)(fneg + (size_t)s * Dn + lane * 4) = bf;
    if (lane == 0) atomicAdd(&hist[labels[s]], 1);

    // ---- last block: exclusive scan of the 2048-bin histogram ----
    __shared__ int s_part[256];
    __shared__ int s_last;
    __syncthreads();
    if (tid == 0) {
        __threadfence();
        s_last = (atomicAdd(ticket, 1) == (int)gridDim.x - 1) ? 1 : 0;
    }
    __syncthreads();
    if (!s_last) return;
    int h[8], pre[8]; int sum = 0;
    #pragma unroll
    for (int j = 0; j < 8; ++j) {
        h[j] = atomicAdd(&hist[tid * 8 + j], 0);   // coherent read
        pre[j] = sum; sum += h[j];
    }
    int vv = sum;
    s_part[tid] = vv; __syncthreads();
    for (int off = 1; off < 256; off <<= 1) {
        int add = (tid >= off) ? s_part[tid - off] : 0;
        __syncthreads();
        vv += add; s_part[tid] = vv;
        __syncthreads();
    }
    const int base = vv - sum;
    #pragma unroll
    for (int j = 0; j < 8; ++j) {
        const int b = tid * 8 + j, o = base + pre[j];
        cnt_i[b] = h[j]; offs[b] = o; offs_wk[b] = o;
    }
}

// ---------------- K2: scatter sample indices by class ---------------------
__global__ __launch_bounds__(256) void k_scatter(const int* __restrict__ labels,
                                                 int* __restrict__ offs_work,
                                                 int* __restrict__ order) {
    const int i = blockIdx.x * 256 + threadIdx.x;
    const int pos = atomicAdd(&offs_work[labels[i]], 1);
    order[pos] = i;
}

// ---------------- K3: per-class sums -> centK (K-major bf16) + cn2 --------
// wave per class; lane covers 4 dims. fneg holds -2f; scale by -0.5.
__global__ __launch_bounds__(256) void k_centseg(const __bf16* __restrict__ fneg,
                                                 const int* __restrict__ order,
                                                 const int* __restrict__ offs,
                                                 const int* __restrict__ cnt_i,
                                                 __bf16* __restrict__ centK,
                                                 float* __restrict__ cn2x) {
    const int wave = threadIdx.x >> 6, lane = threadIdx.x & 63;
    const int c = blockIdx.x * 4 + wave;
    const int n = cnt_i[c], start = offs[c];
    int myidx = 0;
    if (lane < n) myidx = order[start + lane];
    float sx = 0.f, sy = 0.f, sz = 0.f, sw = 0.f;
    const int nf = (n < 64) ? n : 64;
    for (int j = 0; j < nf; ++j) {
        const int idx = __shfl(myidx, j, 64);
        const bf16x4 v = *(const bf16x4*)(fneg + (size_t)idx * Dn + lane * 4);
        sx += -0.5f * (float)v[0]; sy += -0.5f * (float)v[1];
        sz += -0.5f * (float)v[2]; sw += -0.5f * (float)v[3];
    }
    for (int j = 64; j < n; ++j) {          // overflow fallback (rare)
        const int idx = order[start + j];
        const bf16x4 v = *(const bf16x4*)(fneg + (size_t)idx * Dn + lane * 4);
        sx += -0.5f * (float)v[0]; sy += -0.5f * (float)v[1];
        sz += -0.5f * (float)v[2]; sw += -0.5f * (float)v[3];
    }
    const float invn = 1.0f / fmaxf((float)n, 1.0f);
    const float cx = sx * invn, cy = sy * invn, cz = sz * invn, cw = sw * invn;
    // centK chunk (kc, c): dims [8kc,8kc+8); lane covers kc=lane>>1, half lane&1
    bf16x4 cb; cb[0] = (__bf16)cx; cb[1] = (__bf16)cy;
    cb[2] = (__bf16)cz; cb[3] = (__bf16)cw;
    *(bf16x4*)(centK + ((size_t)(lane >> 1) * Cn + c) * 8 + (lane & 1) * 4) = cb;
    float ss = cx * cx + cy * cy + cz * cz + cw * cw;
    #pragma unroll
    for (int off = 1; off < 64; off <<= 1) ss += __shfl_xor(ss, off, 64);
    if (lane == 0) cn2x[c] = (n > 0) ? ss : INFF;
}

// ---------------- K4: MFMA dot + masked min + own-class dot extraction ----
// grid (Bn/256, NSPLIT); block 256 = 4 waves; wave owns 64 samples (4 tiles).
// B staged as 32-class supertiles (2 sub-tiles), double-buffered: 17 barriers
// per unit instead of 33. A = -2f (prescaled), so cn2+acc = d^2-1.
__global__ __launch_bounds__(256, 2) void k_main(const __bf16* __restrict__ fneg,
                                                 const int* __restrict__ labels,
                                                 const __bf16* __restrict__ centK,
                                                 const float* __restrict__ cn2x,
                                                 float* __restrict__ minval,
                                                 float* __restrict__ dotown) {
    __shared__ __align__(16) __bf16 sB[2][32 * Dn];   // 2 x 16KB supertiles
    __shared__ float s_cn2[CLS_PER_BLK];               // 2KB
    const int lane = threadIdx.x & 63, wave = threadIdx.x >> 6;
    const int m16 = lane & 15, quad = lane >> 4;
    const int sbase = blockIdx.x * 256 + wave * 64;
    const int c_begin = blockIdx.y * CLS_PER_BLK;

    // A fragments: a[p][t] = fneg[sbase+16p+m16][32t+8*quad .. +7]
    bf16x8 a[4][8];
    #pragma unroll
    for (int p = 0; p < 4; ++p) {
        const __bf16* fr = fneg + (size_t)(sbase + p * 16 + m16) * Dn + quad * 8;
        #pragma unroll
        for (int t = 0; t < 8; ++t) a[p][t] = *(const bf16x8*)(fr + t * 32);
    }
    int lab[4][4];
    #pragma unroll
    for (int p = 0; p < 4; ++p)
        #pragma unroll
        for (int r = 0; r < 4; ++r)
            lab[p][r] = labels[sbase + p * 16 + quad * 4 + r];

    float rm[4][4], dacc[4][4];
    #pragma unroll
    for (int p = 0; p < 4; ++p)
        #pragma unroll
        for (int r = 0; r < 4; ++r) { rm[p][r] = INFF; dacc[p][r] = 0.0f; }

    // stage supertile s (32 classes = 1024 x 16B chunks) into sB[buf]
    auto stage = [&](int buf, int s) {
        const int c0 = c_begin + s * 32;
        #pragma unroll
        for (int j = 0; j < 4; ++j) {
            const int L = wave * 256 + j * 64 + lane;          // 0..1023
            const int st = L >> 9, kc = (L >> 4) & 31, n = L & 15;
            const __bf16* g = centK + ((size_t)kc * Cn + (c0 + st * 16 + n)) * 8;
            __bf16* l = &sB[buf][(size_t)(wave * 256 + j * 64) * 8]; // wave-uniform
            async_copy16(g, l);
        }
    };

    stage(0, 0);
    for (int c = threadIdx.x; c < CLS_PER_BLK; c += 256) s_cn2[c] = cn2x[c_begin + c];
    __syncthreads();
    for (int s = 0; s < NSUP; ++s) {
        const int cur = s & 1;
        if (s + 1 < NSUP) stage(cur ^ 1, s + 1);
        #pragma unroll
        for (int st = 0; st < 2; ++st) {
            const float cn2v = s_cn2[s * 32 + st * 16 + m16];
            const __bf16* ls = &sB[cur][st * 4096];
            f32x4 acc[4] = {{0.f,0.f,0.f,0.f},{0.f,0.f,0.f,0.f},
                            {0.f,0.f,0.f,0.f},{0.f,0.f,0.f,0.f}};
            #pragma unroll
            for (int t = 0; t < 8; ++t) {
                const bf16x8 b = *(const bf16x8*)(ls + t * 512 + lane * 8);
                #pragma unroll
                for (int p = 0; p < 4; ++p)
                    acc[p] = __builtin_amdgcn_mfma_f32_16x16x32_bf16(a[p][t], b, acc[p], 0, 0, 0);
            }
            const int crow = c_begin + s * 32 + st * 16 + m16;
            #pragma unroll
            for (int p = 0; p < 4; ++p)
                #pragma unroll
                for (int r = 0; r < 4; ++r) {
                    const bool own = (crow == lab[p][r]);
                    const float sel = own ? INFF : cn2v;
                    rm[p][r] = fminf(rm[p][r], sel + acc[p][r]);
                    dacc[p][r] += own ? acc[p][r] : 0.0f;
                }
        }
        __syncthreads();
    }
    #pragma unroll
    for (int off = 1; off < 16; off <<= 1)
        #pragma unroll
        for (int p = 0; p < 4; ++p)
            #pragma unroll
            for (int r = 0; r < 4; ++r) {
                rm[p][r] = fminf(rm[p][r], __shfl_xor(rm[p][r], off, 64));
                dacc[p][r] += __shfl_xor(dacc[p][r], off, 64);
            }
    if (m16 == 0) {
        float* mv = minval + (size_t)blockIdx.y * Bn;
        float* dv = dotown + (size_t)blockIdx.y * Bn;
        #pragma unroll
        for (int p = 0; p < 4; ++p)
            #pragma unroll
            for (int r = 0; r < 4; ++r) {
                mv[sbase + p * 16 + quad * 4 + r] = rm[p][r];
                dv[sbase + p * 16 + quad * 4 + r] = dacc[p][r];
            }
    }
}

// ---------------- K5: d_p (algebraic), d_n, softplus; last block writes out
__global__ __launch_bounds__(256) void k_final(const int* __restrict__ labels,
                                               const int* __restrict__ cnt_i,
                                               const float* __restrict__ cn2x,
                                               const float* __restrict__ minval,
                                               const float* __restrict__ dotown,
                                               const int* __restrict__ epoch,
                                               float* __restrict__ accum,
                                               int* __restrict__ ticket,
                                               float* __restrict__ out) {
    const int tid = threadIdx.x;
    const int i = blockIdx.x * 256 + tid;
    const int lane = tid & 63;
    const float temp = fminf(0.3f + 0.02f * (float)(*epoch), 1.0f);
    float m = minval[i];
    float draw = dotown[i];                 // = -2 * f.c_own (one split nonzero)
    #pragma unroll
    for (int k = 1; k < NSPLIT; ++k) {
        m = fminf(m, minval[(size_t)k * Bn + i]);
        draw += dotown[(size_t)k * Bn + i];
    }
    const int l = labels[i];
    const int n = cnt_i[l];
    const float nf = (float)n;
    const float cn2 = cn2x[l];              // finite (n >= 1)
    const float fds = nf * (-0.5f * draw);  // f.s
    const float fm1 = fmaxf(nf - 1.0f, 1.0f);
    const float fdcp = (fds - 1.0f) / fm1;
    const float cp2 = (nf * nf * cn2 - 2.0f * fds + 1.0f) / (fm1 * fm1);
    const float dp2 = 1.0f - 2.0f * fdcp + cp2;
    const float d_p = sqrtf(fmaxf(dp2, 0.0f) + EPSF);
    const bool finite = (m < 1e37f);
    const float d_n = finite ? sqrtf(fmaxf(1.0f + m, EPSF)) : 0.0f;
    const bool valid = (n > 1) && finite;
    const float x = (d_p - d_n) / temp;
    const float sp = fmaxf(x, 0.0f) + log1pf(expf(-fabsf(x)));
    float ws = valid ? sp : 0.0f, wc = valid ? 1.0f : 0.0f;
    #pragma unroll
    for (int off = 1; off < 64; off <<= 1) {
        ws += __shfl_xor(ws, off, 64);
        wc += __shfl_xor(wc, off, 64);
    }
    if (lane == 0) {
        atomicAdd(&accum[0], ws);
        atomicAdd(&accum[1], wc);
    }
    // ---- last block finalizes ----
    __shared__ int s_last;
    __syncthreads();
    if (tid == 0) {
        __threadfence();
        s_last = (atomicAdd(ticket, 1) == (int)gridDim.x - 1) ? 1 : 0;
    }
    __syncthreads();
    if (s_last && tid == 0) {
        const float s = atomicAdd(&accum[0], 0.0f);   // coherent read
        const float c = atomicAdd(&accum[1], 0.0f);
        out[0] = (c > 0.0f) ? (s / fmaxf(c, 1.0f)) : 0.0f;   // WEIGHT = 1.0
    }
}

// ---------------- launch ---------------------------------------------------
extern "C" void kernel_launch(void* const* d_in, const int* in_sizes, int n_in,
                              void* d_out, int out_size, void* d_ws, size_t ws_size,
                              hipStream_t stream) {
    const float* feat  = (const float*)d_in[0];
    const int* labels  = (const int*)d_in[1];
    const int* epoch   = (const int*)d_in[2];
    float* out = (float*)d_out;
    char* ws = (char*)d_ws;

    size_t off = 0;
    __bf16* fneg   = (__bf16*)(ws + off); off += (size_t)Bn * Dn * 2;      // 16 MiB
    __bf16* centK  = (__bf16*)(ws + off); off += (size_t)Cn * Dn * 2;      //  1 MiB
    float*  cn2x   = (float*)(ws + off);  off += (size_t)Cn * 4;
    int*    cnt_i  = (int*)(ws + off);    off += (size_t)Cn * 4;
    int*    offsp  = (int*)(ws + off);    off += (size_t)Cn * 4;
    int*    offs_wk= (int*)(ws + off);    off += (size_t)Cn * 4;
    int*    order  = (int*)(ws + off);    off += (size_t)Bn * 4;
    float*  minval = (float*)(ws + off);  off += (size_t)NSPLIT * Bn * 4;  // 512 KiB
    float*  dotown = (float*)(ws + off);  off += (size_t)NSPLIT * Bn * 4;  // 512 KiB
    // single contiguous zeroed region: hist | accum | tickets
    int*    hist   = (int*)(ws + off);    off += (size_t)Cn * 4;
    float*  accum  = (float*)(ws + off);  off += 2 * 4;
    int*    ticket = (int*)(ws + off);    off += 2 * 4;   // [0]=prep, [1]=final

    (void)hipMemsetAsync(hist, 0, (size_t)Cn * 4 + 16, stream);

    k_prep<<<Bn / 4, 256, 0, stream>>>(feat, labels, fneg, hist, cnt_i, offsp,
                                       offs_wk, &ticket[0]);
    k_scatter<<<Bn / 256, 256, 0, stream>>>(labels, offs_wk, order);
    k_centseg<<<Cn / 4, 256, 0, stream>>>(fneg, order, offsp, cnt_i, centK, cn2x);
    dim3 g4(Bn / 256, NSPLIT);
    k_main<<<g4, 256, 0, stream>>>(fneg, labels, centK, cn2x, minval, dotown);
    k_final<<<Bn / 256, 256, 0, stream>>>(labels, cnt_i, cn2x, minval, dotown,
                                          epoch, accum, &ticket[1], out);
}

// Round 7
// 178.459 us; speedup vs baseline: 2.2678x; 1.9314x over previous
//
#include <hip/hip_runtime.h>
#include <hip/hip_bf16.h>
#include <math.h>

// Problem constants (fixed by the reference)
constexpr int Bn = 32768;   // batch
constexpr int Dn = 256;     // embedding dim
constexpr int Cn = 2048;    // classes
constexpr int NSPLIT = 4;                // class splits in k_main
constexpr int CLS_PER_BLK = Cn / NSPLIT; // 512
constexpr int NSUP = CLS_PER_BLK / 32;   // 16 supertiles (32 classes) per unit
#define EPSF 1e-12f
#define INFF __builtin_inff()

typedef __bf16 bf16x8 __attribute__((ext_vector_type(8)));
typedef __bf16 bf16x4 __attribute__((ext_vector_type(4)));
typedef float  f32x4  __attribute__((ext_vector_type(4)));

__device__ inline void async_copy16(const void* g, void* l) {
    __builtin_amdgcn_global_load_lds(
        (const __attribute__((address_space(1))) void*)g,
        (__attribute__((address_space(3))) void*)l, 16, 0, 0);
}

// ---------------- K1: normalize(-2x, bf16) + histogram; last block scans --
// 2048 blocks x 4 waves; wave handles 4 samples. fneg[i] = -2 * f_i (bf16).
// NO __threadfence: hist is written and read only via device-scope atomics,
// and __syncthreads' vmcnt(0) drain orders them before the ticket atomic
// (fence's buffer_wbl2 serialized at L2 and cost ~240us in round 6).
__global__ __launch_bounds__(256) void k_prep(const float* __restrict__ feat,
                                              const int* __restrict__ labels,
                                              __bf16* __restrict__ fneg,
                                              int* __restrict__ hist,
                                              int* __restrict__ cnt_i,
                                              int* __restrict__ offs,
                                              int* __restrict__ offs_wk,
                                              int* __restrict__ ticket) {
    const int tid = threadIdx.x;
    const int wave = tid >> 6, lane = tid & 63;
    const int base = blockIdx.x * 16 + wave * 4;
    #pragma unroll
    for (int j = 0; j < 4; ++j) {
        const int s = base + j;
        const float4 v = ((const float4*)(feat + (size_t)s * Dn))[lane];
        float ss = v.x * v.x + v.y * v.y + v.z * v.z + v.w * v.w;
        #pragma unroll
        for (int off = 1; off < 64; off <<= 1) ss += __shfl_xor(ss, off, 64);
        const float inv = -2.0f / fmaxf(sqrtf(ss), EPSF);
        bf16x4 bf;
        bf[0] = (__bf16)(v.x * inv); bf[1] = (__bf16)(v.y * inv);
        bf[2] = (__bf16)(v.z * inv); bf[3] = (__bf16)(v.w * inv);
        *(bf16x4*)(fneg + (size_t)s * Dn + lane * 4) = bf;
        if (lane == 0) atomicAdd(&hist[labels[s]], 1);
    }

    // ---- last block: exclusive scan of the 2048-bin histogram ----
    __shared__ int s_part[256];
    __shared__ int s_last;
    __syncthreads();                      // drains vmcnt -> hist atomics done
    if (tid == 0)
        s_last = (atomicAdd(ticket, 1) == (int)gridDim.x - 1) ? 1 : 0;
    __syncthreads();
    if (!s_last) return;
    int h[8], pre[8]; int sum = 0;
    #pragma unroll
    for (int j = 0; j < 8; ++j) {
        h[j] = atomicAdd(&hist[tid * 8 + j], 0);   // coherent read
        pre[j] = sum; sum += h[j];
    }
    int vv = sum;
    s_part[tid] = vv; __syncthreads();
    for (int off = 1; off < 256; off <<= 1) {
        int add = (tid >= off) ? s_part[tid - off] : 0;
        __syncthreads();
        vv += add; s_part[tid] = vv;
        __syncthreads();
    }
    const int base2 = vv - sum;
    #pragma unroll
    for (int j = 0; j < 8; ++j) {
        const int b = tid * 8 + j, o = base2 + pre[j];
        cnt_i[b] = h[j]; offs[b] = o; offs_wk[b] = o;
    }
}

// ---------------- K2: scatter sample indices by class ---------------------
__global__ __launch_bounds__(256) void k_scatter(const int* __restrict__ labels,
                                                 int* __restrict__ offs_work,
                                                 int* __restrict__ order) {
    const int i = blockIdx.x * 256 + threadIdx.x;
    const int pos = atomicAdd(&offs_work[labels[i]], 1);
    order[pos] = i;
}

// ---------------- K3: per-class sums -> centK (K-major bf16) + cn2 --------
// wave per class; lane covers 4 dims. fneg holds -2f; scale by -0.5.
__global__ __launch_bounds__(256) void k_centseg(const __bf16* __restrict__ fneg,
                                                 const int* __restrict__ order,
                                                 const int* __restrict__ offs,
                                                 const int* __restrict__ cnt_i,
                                                 __bf16* __restrict__ centK,
                                                 float* __restrict__ cn2x) {
    const int wave = threadIdx.x >> 6, lane = threadIdx.x & 63;
    const int c = blockIdx.x * 4 + wave;
    const int n = cnt_i[c], start = offs[c];
    int myidx = 0;
    if (lane < n) myidx = order[start + lane];
    float sx = 0.f, sy = 0.f, sz = 0.f, sw = 0.f;
    const int nf = (n < 64) ? n : 64;
    for (int j = 0; j < nf; ++j) {
        const int idx = __shfl(myidx, j, 64);
        const bf16x4 v = *(const bf16x4*)(fneg + (size_t)idx * Dn + lane * 4);
        sx += -0.5f * (float)v[0]; sy += -0.5f * (float)v[1];
        sz += -0.5f * (float)v[2]; sw += -0.5f * (float)v[3];
    }
    for (int j = 64; j < n; ++j) {          // overflow fallback (rare)
        const int idx = order[start + j];
        const bf16x4 v = *(const bf16x4*)(fneg + (size_t)idx * Dn + lane * 4);
        sx += -0.5f * (float)v[0]; sy += -0.5f * (float)v[1];
        sz += -0.5f * (float)v[2]; sw += -0.5f * (float)v[3];
    }
    const float invn = 1.0f / fmaxf((float)n, 1.0f);
    const float cx = sx * invn, cy = sy * invn, cz = sz * invn, cw = sw * invn;
    // centK chunk (kc, c): dims [8kc,8kc+8); lane covers kc=lane>>1, half lane&1
    bf16x4 cb; cb[0] = (__bf16)cx; cb[1] = (__bf16)cy;
    cb[2] = (__bf16)cz; cb[3] = (__bf16)cw;
    *(bf16x4*)(centK + ((size_t)(lane >> 1) * Cn + c) * 8 + (lane & 1) * 4) = cb;
    float ss = cx * cx + cy * cy + cz * cz + cw * cw;
    #pragma unroll
    for (int off = 1; off < 64; off <<= 1) ss += __shfl_xor(ss, off, 64);
    if (lane == 0) cn2x[c] = (n > 0) ? ss : INFF;
}

// ---------------- K4: MFMA dot + masked min + own-class dot extraction ----
// grid (Bn/256, NSPLIT); block 256 = 4 waves; wave owns 64 samples (4 tiles).
// B staged as 32-class supertiles, double-buffered. A = -2f, so cn2+acc=d^2-1.
__global__ __launch_bounds__(256, 2) void k_main(const __bf16* __restrict__ fneg,
                                                 const int* __restrict__ labels,
                                                 const __bf16* __restrict__ centK,
                                                 const float* __restrict__ cn2x,
                                                 float* __restrict__ minval,
                                                 float* __restrict__ dotown) {
    __shared__ __align__(16) __bf16 sB[2][32 * Dn];   // 2 x 16KB supertiles
    __shared__ float s_cn2[CLS_PER_BLK];               // 2KB
    const int lane = threadIdx.x & 63, wave = threadIdx.x >> 6;
    const int m16 = lane & 15, quad = lane >> 4;
    const int sbase = blockIdx.x * 256 + wave * 64;
    const int c_begin = blockIdx.y * CLS_PER_BLK;

    // A fragments: a[p][t] = fneg[sbase+16p+m16][32t+8*quad .. +7]
    bf16x8 a[4][8];
    #pragma unroll
    for (int p = 0; p < 4; ++p) {
        const __bf16* fr = fneg + (size_t)(sbase + p * 16 + m16) * Dn + quad * 8;
        #pragma unroll
        for (int t = 0; t < 8; ++t) a[p][t] = *(const bf16x8*)(fr + t * 32);
    }
    int lab[4][4];
    #pragma unroll
    for (int p = 0; p < 4; ++p)
        #pragma unroll
        for (int r = 0; r < 4; ++r)
            lab[p][r] = labels[sbase + p * 16 + quad * 4 + r];

    float rm[4][4], dacc[4][4];
    #pragma unroll
    for (int p = 0; p < 4; ++p)
        #pragma unroll
        for (int r = 0; r < 4; ++r) { rm[p][r] = INFF; dacc[p][r] = 0.0f; }

    // stage supertile s (32 classes = 1024 x 16B chunks) into sB[buf]
    auto stage = [&](int buf, int s) {
        const int c0 = c_begin + s * 32;
        #pragma unroll
        for (int j = 0; j < 4; ++j) {
            const int L = wave * 256 + j * 64 + lane;          // 0..1023
            const int st = L >> 9, kc = (L >> 4) & 31, n = L & 15;
            const __bf16* g = centK + ((size_t)kc * Cn + (c0 + st * 16 + n)) * 8;
            __bf16* l = &sB[buf][(size_t)(wave * 256 + j * 64) * 8]; // wave-uniform
            async_copy16(g, l);
        }
    };

    stage(0, 0);
    for (int c = threadIdx.x; c < CLS_PER_BLK; c += 256) s_cn2[c] = cn2x[c_begin + c];
    __syncthreads();
    for (int s = 0; s < NSUP; ++s) {
        const int cur = s & 1;
        if (s + 1 < NSUP) stage(cur ^ 1, s + 1);
        #pragma unroll
        for (int st = 0; st < 2; ++st) {
            const float cn2v = s_cn2[s * 32 + st * 16 + m16];
            const __bf16* ls = &sB[cur][st * 4096];
            f32x4 acc[4] = {{0.f,0.f,0.f,0.f},{0.f,0.f,0.f,0.f},
                            {0.f,0.f,0.f,0.f},{0.f,0.f,0.f,0.f}};
            #pragma unroll
            for (int t = 0; t < 8; ++t) {
                const bf16x8 b = *(const bf16x8*)(ls + t * 512 + lane * 8);
                #pragma unroll
                for (int p = 0; p < 4; ++p)
                    acc[p] = __builtin_amdgcn_mfma_f32_16x16x32_bf16(a[p][t], b, acc[p], 0, 0, 0);
            }
            const int crow = c_begin + s * 32 + st * 16 + m16;
            #pragma unroll
            for (int p = 0; p < 4; ++p)
                #pragma unroll
                for (int r = 0; r < 4; ++r) {
                    const bool own = (crow == lab[p][r]);
                    const float sel = own ? INFF : cn2v;
                    rm[p][r] = fminf(rm[p][r], sel + acc[p][r]);
                    dacc[p][r] += own ? acc[p][r] : 0.0f;
                }
        }
        __syncthreads();
    }
    #pragma unroll
    for (int off = 1; off < 16; off <<= 1)
        #pragma unroll
        for (int p = 0; p < 4; ++p)
            #pragma unroll
            for (int r = 0; r < 4; ++r) {
                rm[p][r] = fminf(rm[p][r], __shfl_xor(rm[p][r], off, 64));
                dacc[p][r] += __shfl_xor(dacc[p][r], off, 64);
            }
    if (m16 == 0) {
        float* mv = minval + (size_t)blockIdx.y * Bn;
        float* dv = dotown + (size_t)blockIdx.y * Bn;
        #pragma unroll
        for (int p = 0; p < 4; ++p)
            #pragma unroll
            for (int r = 0; r < 4; ++r) {
                mv[sbase + p * 16 + quad * 4 + r] = rm[p][r];
                dv[sbase + p * 16 + quad * 4 + r] = dacc[p][r];
            }
    }
}

// ---------------- K5: d_p (algebraic), d_n, softplus; last block writes out
// Fence-free last-block pattern (accum via atomics only; see k_prep note).
__global__ __launch_bounds__(256) void k_final(const int* __restrict__ labels,
                                               const int* __restrict__ cnt_i,
                                               const float* __restrict__ cn2x,
                                               const float* __restrict__ minval,
                                               const float* __restrict__ dotown,
                                               const int* __restrict__ epoch,
                                               float* __restrict__ accum,
                                               int* __restrict__ ticket,
                                               float* __restrict__ out) {
    const int tid = threadIdx.x;
    const int i = blockIdx.x * 256 + tid;
    const int lane = tid & 63;
    const float temp = fminf(0.3f + 0.02f * (float)(*epoch), 1.0f);
    float m = minval[i];
    float draw = dotown[i];                 // = -2 * f.c_own (one split nonzero)
    #pragma unroll
    for (int k = 1; k < NSPLIT; ++k) {
        m = fminf(m, minval[(size_t)k * Bn + i]);
        draw += dotown[(size_t)k * Bn + i];
    }
    const int l = labels[i];
    const int n = cnt_i[l];
    const float nf = (float)n;
    const float cn2 = cn2x[l];              // finite (n >= 1)
    const float fds = nf * (-0.5f * draw);  // f.s
    const float fm1 = fmaxf(nf - 1.0f, 1.0f);
    const float fdcp = (fds - 1.0f) / fm1;
    const float cp2 = (nf * nf * cn2 - 2.0f * fds + 1.0f) / (fm1 * fm1);
    const float dp2 = 1.0f - 2.0f * fdcp + cp2;
    const float d_p = sqrtf(fmaxf(dp2, 0.0f) + EPSF);
    const bool finite = (m < 1e37f);
    const float d_n = finite ? sqrtf(fmaxf(1.0f + m, EPSF)) : 0.0f;
    const bool valid = (n > 1) && finite;
    const float x = (d_p - d_n) / temp;
    const float sp = fmaxf(x, 0.0f) + log1pf(expf(-fabsf(x)));
    float ws = valid ? sp : 0.0f, wc = valid ? 1.0f : 0.0f;
    #pragma unroll
    for (int off = 1; off < 64; off <<= 1) {
        ws += __shfl_xor(ws, off, 64);
        wc += __shfl_xor(wc, off, 64);
    }
    if (lane == 0) {
        atomicAdd(&accum[0], ws);
        atomicAdd(&accum[1], wc);
    }
    // ---- last block finalizes ----
    __shared__ int s_last;
    __syncthreads();                       // drains vmcnt -> accum atomics done
    if (tid == 0)
        s_last = (atomicAdd(ticket, 1) == (int)gridDim.x - 1) ? 1 : 0;
    __syncthreads();
    if (s_last && tid == 0) {
        const float s = atomicAdd(&accum[0], 0.0f);   // coherent read
        const float c = atomicAdd(&accum[1], 0.0f);
        out[0] = (c > 0.0f) ? (s / fmaxf(c, 1.0f)) : 0.0f;   // WEIGHT = 1.0
    }
}

// ---------------- launch ---------------------------------------------------
extern "C" void kernel_launch(void* const* d_in, const int* in_sizes, int n_in,
                              void* d_out, int out_size, void* d_ws, size_t ws_size,
                              hipStream_t stream) {
    const float* feat  = (const float*)d_in[0];
    const int* labels  = (const int*)d_in[1];
    const int* epoch   = (const int*)d_in[2];
    float* out = (float*)d_out;
    char* ws = (char*)d_ws;

    size_t off = 0;
    __bf16* fneg   = (__bf16*)(ws + off); off += (size_t)Bn * Dn * 2;      // 16 MiB
    __bf16* centK  = (__bf16*)(ws + off); off += (size_t)Cn * Dn * 2;      //  1 MiB
    float*  cn2x   = (float*)(ws + off);  off += (size_t)Cn * 4;
    int*    cnt_i  = (int*)(ws + off);    off += (size_t)Cn * 4;
    int*    offsp  = (int*)(ws + off);    off += (size_t)Cn * 4;
    int*    offs_wk= (int*)(ws + off);    off += (size_t)Cn * 4;
    int*    order  = (int*)(ws + off);    off += (size_t)Bn * 4;
    float*  minval = (float*)(ws + off);  off += (size_t)NSPLIT * Bn * 4;  // 512 KiB
    float*  dotown = (float*)(ws + off);  off += (size_t)NSPLIT * Bn * 4;  // 512 KiB
    // single contiguous zeroed region: hist | accum | tickets
    int*    hist   = (int*)(ws + off);    off += (size_t)Cn * 4;
    float*  accum  = (float*)(ws + off);  off += 2 * 4;
    int*    ticket = (int*)(ws + off);    off += 2 * 4;   // [0]=prep, [1]=final

    (void)hipMemsetAsync(hist, 0, (size_t)Cn * 4 + 16, stream);

    k_prep<<<Bn / 16, 256, 0, stream>>>(feat, labels, fneg, hist, cnt_i, offsp,
                                        offs_wk, &ticket[0]);
    k_scatter<<<Bn / 256, 256, 0, stream>>>(labels, offs_wk, order);
    k_centseg<<<Cn / 4, 256, 0, stream>>>(fneg, order, offsp, cnt_i, centK, cn2x);
    dim3 g4(Bn / 256, NSPLIT);
    k_main<<<g4, 256, 0, stream>>>(fneg, labels, centK, cn2x, minval, dotown);
    k_final<<<Bn / 256, 256, 0, stream>>>(labels, cnt_i, cn2x, minval, dotown,
                                          epoch, accum, &ticket[1], out);
}